// Round 2
// baseline (581.290 us; speedup 1.0000x reference)
//
#include <hip/hip_runtime.h>

// Problem constants (B=32, C=3, H=W=512, P=16, EMBED=768, HEAD_DIM=64)
#define N_TOK   32768     // 32 * 32 * 32 tokens
#define EMBED_D 768
#define K_DIM   768       // 3*16*16

// Output layout (flat float, concatenated in reference return order)
constexpr long long OFF_TOKENS = 0;                       // 32768*768
constexpr long long OFF_CU     = 25165824LL;              // 33
constexpr long long OFF_COORDS = 25165857LL;              // 32768*2
constexpr long long OFF_COS    = 25231393LL;              // 32768*64
constexpr long long OFF_SIN    = 27328545LL;              // 32768*64
constexpr long long OFF_ISP    = 29425697LL;              // 32768

// ---------------------------------------------------------------------------
// Fused patchify + SGEMM (fp32).
// tokens[m][n] = sum_k patch(m,k) * W[k][n] + b[n]
// m = b*1024 + hp*32 + wp ; k = c*256 + p1*16 + p2
// patch(m,k) = img[b][c][hp*16+p1][wp*16+p2]
// Tile: BM=128, BN=128, BK=16; 256 threads; 8x8 per-thread microtile.
// ---------------------------------------------------------------------------
__global__ __launch_bounds__(256) void patch_gemm(
    const float* __restrict__ img, const float* __restrict__ Wp,
    const float* __restrict__ bias, float* __restrict__ out)
{
    __shared__ float As[16][128];   // [k][m]
    __shared__ float Bs[16][128];   // [k][n]

    const int tid = threadIdx.x;
    const int bn  = blockIdx.x;     // 0..5   (N tiles)
    const int bm  = blockIdx.y;     // 0..255 (M tiles)

    const int tx = tid & 15;        // N dir
    const int ty = tid >> 4;        // M dir

    // ---- A loader mapping: each thread owns row lm, quads {lq, lq+2} ----
    const int lm = tid & 127;
    const int lq = tid >> 7;                 // 0 or 1
    const int m  = bm * 128 + lm;
    const int bb = m >> 10;                  // batch
    const int hp = (m & 1023) >> 5;
    const int wq = m & 31;
    // base: img + b*C*H*W + (hp*16)*W + wp*16 + p2_base ; per kt add c*H*W + p1*W
    const float* abase = img + (size_t)bb * 786432 + (size_t)hp * 8192 + wq * 16 + lq * 4;

    // ---- B loader mapping: thread owns rows {kb, kb+8}, float4 col nb4 ----
    const int nb4 = tid & 31;
    const int kb  = tid >> 5;                // 0..7
    const float* wbase = Wp + (size_t)kb * 768 + bn * 128 + nb4 * 4;

    float acc[8][8];
    #pragma unroll
    for (int i = 0; i < 8; i++)
        #pragma unroll
        for (int j = 0; j < 8; j++) acc[i][j] = 0.f;

    for (int kt = 0; kt < 48; ++kt) {
        // global loads for this K-slab (16 contiguous floats per A row)
        const float* ap = abase + (kt >> 4) * 262144 + (kt & 15) * 512;
        const float4 a0 = *(const float4*)ap;
        const float4 a1 = *(const float4*)(ap + 8);
        const float* bp = wbase + (size_t)kt * 16 * 768;
        const float4 b0 = *(const float4*)bp;
        const float4 b1 = *(const float4*)(bp + 8 * 768);

        __syncthreads();   // previous iteration's LDS reads complete
        const int k0 = lq * 4;
        As[k0 + 0][lm] = a0.x; As[k0 + 1][lm] = a0.y;
        As[k0 + 2][lm] = a0.z; As[k0 + 3][lm] = a0.w;
        As[k0 + 8][lm] = a1.x; As[k0 + 9][lm] = a1.y;
        As[k0 +10][lm] = a1.z; As[k0 +11][lm] = a1.w;
        *(float4*)&Bs[kb][nb4 * 4]     = b0;
        *(float4*)&Bs[kb + 8][nb4 * 4] = b1;
        __syncthreads();

        #pragma unroll
        for (int k = 0; k < 16; k++) {
            float af[8], bf[8];
            #pragma unroll
            for (int i = 0; i < 8; i++) af[i] = As[k][ty * 8 + i];
            #pragma unroll
            for (int j = 0; j < 8; j++) bf[j] = Bs[k][tx * 8 + j];
            #pragma unroll
            for (int i = 0; i < 8; i++)
                #pragma unroll
                for (int j = 0; j < 8; j++)
                    acc[i][j] = fmaf(af[i], bf[j], acc[i][j]);
        }
    }

    // ---- epilogue: add bias, vectorized store ----
    const int gm = bm * 128 + ty * 8;
    const int gn = bn * 128 + tx * 8;
    float bv[8];
    #pragma unroll
    for (int j = 0; j < 8; j++) bv[j] = bias[gn + j];
    #pragma unroll
    for (int i = 0; i < 8; i++) {
        float* op = out + OFF_TOKENS + (size_t)(gm + i) * 768 + gn;
        float4 v0 = make_float4(acc[i][0] + bv[0], acc[i][1] + bv[1],
                                acc[i][2] + bv[2], acc[i][3] + bv[3]);
        float4 v1 = make_float4(acc[i][4] + bv[4], acc[i][5] + bv[5],
                                acc[i][6] + bv[6], acc[i][7] + bv[7]);
        *(float4*)op       = v0;
        *(float4*)(op + 4) = v1;
    }
}

// ---------------------------------------------------------------------------
// Side outputs: cu_seqlens, patch_coords, rope cos/sin, is_patch.
// One thread per (token, head_dim) element for rope; d==0 threads also emit
// coords / is_patch; first 33 tokens' d==1 thread emits cu_seqlens.
// ---------------------------------------------------------------------------
__global__ __launch_bounds__(256) void aux_kernel(float* __restrict__ out)
{
    const int idx = blockIdx.x * 256 + threadIdx.x;     // 0 .. 32768*64-1
    if (idx >= N_TOK * 64) return;
    const int n = idx >> 6;
    const int d = idx & 63;

    const int hp = (n & 1023) >> 5;
    const int wp = n & 31;

    const int coord = (d < 32) ? hp : wp;
    const int j = (d & 31) >> 1;                        // freq index 0..15
    // inv_freq = 10000^(-j/16) = 2^(-j * log2(10000)/16)
    const float freq = exp2f(-(float)j * 0.8304820237218406f);
    const float ang  = (float)coord * freq;
    float s, c;
    sincosf(ang, &s, &c);

    out[OFF_COS + idx] = c;
    out[OFF_SIN + idx] = s;

    if (d == 0) {
        out[OFF_COORDS + 2 * (long long)n]     = (float)hp;
        out[OFF_COORDS + 2 * (long long)n + 1] = (float)wp;
        out[OFF_ISP + n] = 1.0f;
    }
    if (d == 1 && n < 33) {
        out[OFF_CU + n] = (float)(n * 1024);
    }
}

extern "C" void kernel_launch(void* const* d_in, const int* in_sizes, int n_in,
                              void* d_out, int out_size, void* d_ws, size_t ws_size,
                              hipStream_t stream) {
    const float* img  = (const float*)d_in[0];   // (32,3,512,512)
    const float* Wp   = (const float*)d_in[1];   // (768,768)
    const float* bias = (const float*)d_in[2];   // (768,)
    float* out = (float*)d_out;

    dim3 ggrid(6, 256);            // (N tiles, M tiles)
    patch_gemm<<<ggrid, 256, 0, stream>>>(img, Wp, bias, out);

    const int aux_elems = N_TOK * 64;
    aux_kernel<<<(aux_elems + 255) / 256, 256, 0, stream>>>(out);
}

// Round 3
// 314.765 us; speedup vs baseline: 1.8467x; 1.8467x over previous
//
#include <hip/hip_runtime.h>
#include <hip/hip_bf16.h>

typedef unsigned short u16;
typedef unsigned int   u32;
typedef __bf16 bf16x8 __attribute__((ext_vector_type(8)));
typedef float  f32x4  __attribute__((ext_vector_type(4)));

#define N_TOK 32768
constexpr long long OFF_TOKENS = 0;                       // 32768*768
constexpr long long OFF_CU     = 25165824LL;              // 33
constexpr long long OFF_COORDS = 25165857LL;              // 32768*2
constexpr long long OFF_COS    = 25231393LL;              // 32768*64
constexpr long long OFF_SIN    = 27328545LL;              // 32768*64
constexpr long long OFF_ISP    = 29425697LL;              // 32768

// split v ~= h + l, each bf16 (RNE). ~17 mantissa bits total.
__device__ __forceinline__ void split_bf16(float v, u32& h, u32& l) {
    __hip_bfloat16 bh = __float2bfloat16(v);
    float fh = __bfloat162float(bh);
    __hip_bfloat16 bl = __float2bfloat16(v - fh);
    h = (u32)__builtin_bit_cast(u16, bh);
    l = (u32)__builtin_bit_cast(u16, bl);
}

// ---------------------------------------------------------------------------
// One-time: W[k][n] fp32 -> Wt_h[n][k], Wt_l[n][k] bf16 in workspace.
// (Both MFMA operands need k-contiguous per lane, so transpose W once here
//  instead of per-tile in LDS.)
// ---------------------------------------------------------------------------
__global__ __launch_bounds__(256) void prep_w(const float* __restrict__ W,
                                              u16* __restrict__ wt) {
    int idx = blockIdx.x * 256 + threadIdx.x;
    if (idx >= 768 * 768) return;
    int k = idx / 768;
    int n = idx - k * 768;
    u32 h, l;
    split_bf16(W[idx], h, l);
    wt[(size_t)n * 768 + k]          = (u16)h;
    wt[589824 + (size_t)n * 768 + k] = (u16)l;   // 589824 = 768*768
}

// ---------------------------------------------------------------------------
// Fused patchify + 3-pass split-bf16 MFMA GEMM.
// tokens[m][n] = sum_k A(m,k) W[k][n] + b[n];  A = patchified images (fp32).
// BM=128 BN=128 BK=32; 4 waves; per-wave 64x64 = 4x4 frags of 16x16x32.
// LDS rows are 64B; st_16x32 swizzle: byte ^= (row&8)<<2  (32B-slot XOR).
// ---------------------------------------------------------------------------
__global__ __launch_bounds__(256) void patch_gemm_mfma(
    const float* __restrict__ img, const u16* __restrict__ wt,
    const float* __restrict__ bias, float* __restrict__ out)
{
    __shared__ __align__(16) char smem[32768];
    char* pAh = smem;            // As_h[128][32] bf16
    char* pAl = smem + 8192;     // As_l
    char* pBh = smem + 16384;    // Bs_h[128 n][32 k] bf16
    char* pBl = smem + 24576;    // Bs_l

    const int tid = threadIdx.x;
    const int bn  = blockIdx.x;      // 0..5
    const int bm  = blockIdx.y;      // 0..255

    const int lane = tid & 63;
    const int wid  = tid >> 6;       // 0..3
    const int wm   = (wid >> 1) << 6;  // wave row offset (0/64)
    const int wn   = (wid & 1) << 6;   // wave col offset (0/64)
    const int lr   = lane & 15;
    const int lg   = lane >> 4;      // 0..3 -> k-offset lg*8

    // ---- A staging mapping: thread = (row am, k-half alq) ----
    const int am  = tid & 127;
    const int alq = tid >> 7;                    // 0/1 -> k 0-15 / 16-31
    const int m   = bm * 128 + am;
    const int bb  = m >> 10;
    const int hp  = (m & 1023) >> 5;
    const int wq  = m & 31;
    const float* abase = img + (size_t)bb * 786432 + (size_t)hp * 8192 + wq * 16;
    const int a_wb = am * 64 + ((alq ^ ((am >> 3) & 1)) << 5);   // swizzled byte

    // ---- B staging mapping: thread = (col bnl, k-half blq) ----
    const int bnl = tid >> 1;                    // 0..127
    const int blq = tid & 1;
    const u16* wbh = wt + (size_t)(bn * 128 + bnl) * 768 + blq * 16;
    const u16* wbl = wbh + 589824;
    const int b_wb = bnl * 64 + ((blq ^ ((bnl >> 3) & 1)) << 5);

    // ---- fragment-read byte offsets (row-part added per frag) ----
    const int swz  = (lr >> 3) & 1;
    const int a_rd = lr * 64 + (((lg >> 1) ^ swz) << 5) + ((lg & 1) << 4);
    // same formula for B (rows are n there)

    f32x4 acc[4][4];
    #pragma unroll
    for (int i = 0; i < 4; i++)
        #pragma unroll
        for (int j = 0; j < 4; j++) acc[i][j] = {0.f, 0.f, 0.f, 0.f};

    #pragma unroll 1
    for (int kt = 0; kt < 24; ++kt) {
        // ---- global loads (A fp32 slab: 2 image rows; B bf16 pre-split) ----
        const float* ap = abase + (kt >> 3) * 262144 + ((kt & 7) * 2 + alq) * 512;
        float4 a0 = *(const float4*)(ap);
        float4 a1 = *(const float4*)(ap + 4);
        float4 a2 = *(const float4*)(ap + 8);
        float4 a3 = *(const float4*)(ap + 12);
        const u16* ph = wbh + kt * 32;
        uint4 wh0 = *(const uint4*)(ph);
        uint4 wh1 = *(const uint4*)(ph + 8);
        const u16* pl = wbl + kt * 32;
        uint4 wl0 = *(const uint4*)(pl);
        uint4 wl1 = *(const uint4*)(pl + 8);

        __syncthreads();   // prev iteration's LDS reads done before overwrite

        // ---- convert/split A: 16 fp32 -> 8+8 bf16 h/l, packed ----
        u32 h0,l0,h1,l1,h2,l2,h3,l3;
        uint4 H, L;
        split_bf16(a0.x,h0,l0); split_bf16(a0.y,h1,l1);
        split_bf16(a0.z,h2,l2); split_bf16(a0.w,h3,l3);
        H.x = h0 | (h1 << 16); L.x = l0 | (l1 << 16);
        H.y = h2 | (h3 << 16); L.y = l2 | (l3 << 16);
        split_bf16(a1.x,h0,l0); split_bf16(a1.y,h1,l1);
        split_bf16(a1.z,h2,l2); split_bf16(a1.w,h3,l3);
        H.z = h0 | (h1 << 16); L.z = l0 | (l1 << 16);
        H.w = h2 | (h3 << 16); L.w = l2 | (l3 << 16);
        *(uint4*)(pAh + a_wb) = H;
        *(uint4*)(pAl + a_wb) = L;
        split_bf16(a2.x,h0,l0); split_bf16(a2.y,h1,l1);
        split_bf16(a2.z,h2,l2); split_bf16(a2.w,h3,l3);
        H.x = h0 | (h1 << 16); L.x = l0 | (l1 << 16);
        H.y = h2 | (h3 << 16); L.y = l2 | (l3 << 16);
        split_bf16(a3.x,h0,l0); split_bf16(a3.y,h1,l1);
        split_bf16(a3.z,h2,l2); split_bf16(a3.w,h3,l3);
        H.z = h0 | (h1 << 16); L.z = l0 | (l1 << 16);
        H.w = h2 | (h3 << 16); L.w = l2 | (l3 << 16);
        *(uint4*)(pAh + a_wb + 16) = H;
        *(uint4*)(pAl + a_wb + 16) = L;

        // ---- B: straight bf16 copy into LDS ----
        *(uint4*)(pBh + b_wb)      = wh0;
        *(uint4*)(pBh + b_wb + 16) = wh1;
        *(uint4*)(pBl + b_wb)      = wl0;
        *(uint4*)(pBl + b_wb + 16) = wl1;

        __syncthreads();

        // ---- fragment reads ----
        bf16x8 ah[4], al[4], bh4[4], bl4[4];
        #pragma unroll
        for (int i = 0; i < 4; i++) {
            const int off = (wm + i * 16) * 64 + a_rd;
            ah[i] = *(const bf16x8*)(pAh + off);
            al[i] = *(const bf16x8*)(pAl + off);
        }
        #pragma unroll
        for (int j = 0; j < 4; j++) {
            const int off = (wn + j * 16) * 64 + a_rd;  // same lane formula
            bh4[j] = *(const bf16x8*)(pBh + off);
            bl4[j] = *(const bf16x8*)(pBl + off);
        }

        // ---- 3-pass MFMA ----
        #pragma unroll
        for (int i = 0; i < 4; i++)
            #pragma unroll
            for (int j = 0; j < 4; j++) {
                acc[i][j] = __builtin_amdgcn_mfma_f32_16x16x32_bf16(ah[i], bh4[j], acc[i][j], 0, 0, 0);
                acc[i][j] = __builtin_amdgcn_mfma_f32_16x16x32_bf16(ah[i], bl4[j], acc[i][j], 0, 0, 0);
                acc[i][j] = __builtin_amdgcn_mfma_f32_16x16x32_bf16(al[i], bh4[j], acc[i][j], 0, 0, 0);
            }
    }

    // ---- epilogue: bias + store (C/D: col=lane&15, row=(lane>>4)*4+r) ----
    float bv[4];
    #pragma unroll
    for (int j = 0; j < 4; j++) bv[j] = bias[bn * 128 + wn + j * 16 + lr];
    #pragma unroll
    for (int i = 0; i < 4; i++) {
        const int rb = bm * 128 + wm + i * 16 + lg * 4;
        #pragma unroll
        for (int j = 0; j < 4; j++) {
            const int cg = bn * 128 + wn + j * 16 + lr;
            #pragma unroll
            for (int r = 0; r < 4; r++)
                out[OFF_TOKENS + (size_t)(rb + r) * 768 + cg] = acc[i][j][r] + bv[j];
        }
    }
}

// ---------------------------------------------------------------------------
// Side outputs. Thread per (token, freq-pair): rope repeats each freq twice,
// so one sincos serves two d's (float2 store).
// ---------------------------------------------------------------------------
__global__ __launch_bounds__(256) void aux_kernel(float* __restrict__ out)
{
    const int idx = blockIdx.x * 256 + threadIdx.x;     // 0 .. 32768*32-1
    if (idx >= N_TOK * 32) return;
    const int n  = idx >> 5;
    const int jd = idx & 31;

    const int hp = (n & 1023) >> 5;
    const int wp = n & 31;

    const int coord = (jd < 16) ? hp : wp;
    const int j = jd & 15;
    const float freq = exp2f(-(float)j * 0.8304820237218406f);  // 10000^(-j/16)
    float s, c;
    sincosf((float)coord * freq, &s, &c);

    const long long off = (long long)n * 64 + jd * 2;
    *(float2*)(out + OFF_COS + off) = make_float2(c, c);
    *(float2*)(out + OFF_SIN + off) = make_float2(s, s);

    if (jd == 0) {
        out[OFF_COORDS + 2 * (long long)n]     = (float)hp;
        out[OFF_COORDS + 2 * (long long)n + 1] = (float)wp;
        out[OFF_ISP + n] = 1.0f;
    }
    if (jd == 1 && n < 33) {
        out[OFF_CU + n] = (float)(n * 1024);
    }
}

extern "C" void kernel_launch(void* const* d_in, const int* in_sizes, int n_in,
                              void* d_out, int out_size, void* d_ws, size_t ws_size,
                              hipStream_t stream) {
    const float* img  = (const float*)d_in[0];   // (32,3,512,512)
    const float* W    = (const float*)d_in[1];   // (768,768)
    const float* bias = (const float*)d_in[2];   // (768,)
    float* out = (float*)d_out;
    u16* wt = (u16*)d_ws;                        // needs 2*768*768*2 = 2.36 MB

    prep_w<<<2304, 256, 0, stream>>>(W, wt);

    dim3 ggrid(6, 256);            // (N tiles, M tiles)
    patch_gemm_mfma<<<ggrid, 256, 0, stream>>>(img, wt, bias, out);

    const int aux_elems = N_TOK * 32;
    aux_kernel<<<(aux_elems + 255) / 256, 256, 0, stream>>>(out);
}

// Round 5
// 289.763 us; speedup vs baseline: 2.0061x; 1.0863x over previous
//
#include <hip/hip_runtime.h>
#include <hip/hip_bf16.h>

typedef unsigned short u16;
typedef unsigned int   u32;
typedef __bf16 bf16x8 __attribute__((ext_vector_type(8)));
typedef float  f32x4  __attribute__((ext_vector_type(4)));

#define N_TOK 32768
constexpr long long OFF_TOKENS = 0;                       // 32768*768
constexpr long long OFF_CU     = 25165824LL;              // 33
constexpr long long OFF_COORDS = 25165857LL;              // 32768*2
constexpr long long OFF_COS    = 25231393LL;              // 32768*64
constexpr long long OFF_SIN    = 27328545LL;              // 32768*64
constexpr long long OFF_ISP    = 29425697LL;              // 32768

__device__ __forceinline__ void split_bf16(float v, u16& h, u16& l) {
    __hip_bfloat16 bh = __float2bfloat16(v);
    float fh = __bfloat162float(bh);
    __hip_bfloat16 bl = __float2bfloat16(v - fh);
    h = __builtin_bit_cast(u16, bh);
    l = __builtin_bit_cast(u16, bl);
}

__device__ __forceinline__ u32 pk2(float lo, float hi) {
    u32 a = (u32)__builtin_bit_cast(u16, __float2bfloat16(lo));
    u32 b = (u32)__builtin_bit_cast(u16, __float2bfloat16(hi));
    return a | (b << 16);
}

// ---------------------------------------------------------------------------
// W[k][n] fp32 -> Wt_h[n][k], Wt_l[n][k] bf16 (one-time, workspace).
// Thread owns 8 consecutive k of one column n: scattered L2-hit reads,
// fully-coalesced 16B stores.
// ---------------------------------------------------------------------------
__global__ __launch_bounds__(128) void prep_w(const float* __restrict__ W,
                                              u16* __restrict__ wt) {
    const int n  = blockIdx.x;        // 0..767
    const int kg = threadIdx.x;       // 0..127, active < 96
    if (kg >= 96) return;
    u16 h[8], l[8];
    #pragma unroll
    for (int r = 0; r < 8; r++)
        split_bf16(W[(size_t)(kg * 8 + r) * 768 + n], h[r], l[r]);
    uint4 H, L;
    H.x = (u32)h[0] | ((u32)h[1] << 16); H.y = (u32)h[2] | ((u32)h[3] << 16);
    H.z = (u32)h[4] | ((u32)h[5] << 16); H.w = (u32)h[6] | ((u32)h[7] << 16);
    L.x = (u32)l[0] | ((u32)l[1] << 16); L.y = (u32)l[2] | ((u32)l[3] << 16);
    L.z = (u32)l[4] | ((u32)l[5] << 16); L.w = (u32)l[6] | ((u32)l[7] << 16);
    *(uint4*)&wt[(size_t)n * 768 + kg * 8]          = H;
    *(uint4*)&wt[589824 + (size_t)n * 768 + kg * 8] = L;
}

// ---------------------------------------------------------------------------
// Fused patchify + 2-pass split-bf16 MFMA GEMM:
//   tokens ~= Ah·(Bh + Bl) + bias   (A-low dropped; error ~6e-3 absmax)
// BM=128 BN=128 BK=32; 4 waves; per-wave 64x64 = 4x4 frags of 16x16x32.
// Register-prefetch 2-phase: issue kt+1 global loads before compute(kt).
// LDS rows 64B, st-swizzle: 32B slot ^= row bit3.
// ---------------------------------------------------------------------------
__global__ __launch_bounds__(256) void patch_gemm_mfma(
    const float* __restrict__ img, const u16* __restrict__ wt,
    const float* __restrict__ bias, float* __restrict__ out)
{
    __shared__ __align__(16) char smem[24576];
    char* pAh = smem;            // Ah[128 m][32 k] bf16
    char* pBh = smem + 8192;     // Bh[128 n][32 k]
    char* pBl = smem + 16384;    // Bl[128 n][32 k]

    const int tid = threadIdx.x;
    const int bn  = blockIdx.x;      // 0..5
    const int bm  = blockIdx.y;      // 0..255

    const int lane = tid & 63;
    const int wid  = tid >> 6;
    const int wm   = (wid >> 1) << 6;
    const int wn   = (wid & 1) << 6;
    const int lr   = lane & 15;
    const int lg   = lane >> 4;

    // A staging: thread = (row am, k-half alq); 16 contiguous fp32 per row-half
    const int am  = tid & 127;
    const int alq = tid >> 7;
    const int m   = bm * 128 + am;
    const int bb  = m >> 10;
    const int hp  = (m & 1023) >> 5;
    const int wq  = m & 31;
    const float* abase = img + (size_t)bb * 786432 + (size_t)hp * 8192 + wq * 16;
    const int a_wb = am * 64 + ((alq ^ ((am >> 3) & 1)) << 5);

    // B staging: thread = (col bnl, k-half blq)
    const int bnl = tid >> 1;
    const int blq = tid & 1;
    const u16* wbh = wt + (size_t)(bn * 128 + bnl) * 768 + blq * 16;
    const u16* wbl = wbh + 589824;
    const int b_wb = bnl * 64 + ((blq ^ ((bnl >> 3) & 1)) << 5);

    // fragment-read byte offset (row base added per frag; row&8 == lr&8)
    const int swz  = (lr >> 3) & 1;
    const int a_rd = lr * 64 + (((lg >> 1) ^ swz) << 5) + ((lg & 1) << 4);

    f32x4 acc[4][4];
    #pragma unroll
    for (int i = 0; i < 4; i++)
        #pragma unroll
        for (int j = 0; j < 4; j++) acc[i][j] = {0.f, 0.f, 0.f, 0.f};

    float4 a0, a1, a2, a3;
    uint4 wh0, wh1, wl0, wl1;

#define LOAD_T(KT)                                                          \
    {   const float* ap = abase + ((KT) >> 3) * 262144 +                    \
                          (((KT) & 7) * 2 + alq) * 512;                     \
        a0 = *(const float4*)(ap);      a1 = *(const float4*)(ap + 4);      \
        a2 = *(const float4*)(ap + 8);  a3 = *(const float4*)(ap + 12);     \
        const u16* ph = wbh + (KT) * 32;                                    \
        wh0 = *(const uint4*)(ph);      wh1 = *(const uint4*)(ph + 8);      \
        const u16* pl = wbl + (KT) * 32;                                    \
        wl0 = *(const uint4*)(pl);      wl1 = *(const uint4*)(pl + 8); }

    LOAD_T(0);

    #pragma unroll 1
    for (int kt = 0; kt < 24; ++kt) {
        __syncthreads();   // prev iteration's LDS reads complete

        // convert A (h only) + stage
        uint4 H;
        H.x = pk2(a0.x, a0.y); H.y = pk2(a0.z, a0.w);
        H.z = pk2(a1.x, a1.y); H.w = pk2(a1.z, a1.w);
        *(uint4*)(pAh + a_wb) = H;
        H.x = pk2(a2.x, a2.y); H.y = pk2(a2.z, a2.w);
        H.z = pk2(a3.x, a3.y); H.w = pk2(a3.z, a3.w);
        *(uint4*)(pAh + a_wb + 16) = H;
        *(uint4*)(pBh + b_wb)      = wh0;
        *(uint4*)(pBh + b_wb + 16) = wh1;
        *(uint4*)(pBl + b_wb)      = wl0;
        *(uint4*)(pBl + b_wb + 16) = wl1;

        // prefetch next slab into regs (latency hides under MFMA below)
        if (kt < 23) LOAD_T(kt + 1);

        __syncthreads();

        bf16x8 ah[4], bh4[4], bl4[4];
        #pragma unroll
        for (int i = 0; i < 4; i++)
            ah[i] = *(const bf16x8*)(pAh + (wm + i * 16) * 64 + a_rd);
        #pragma unroll
        for (int j = 0; j < 4; j++) {
            const int off = (wn + j * 16) * 64 + a_rd;
            bh4[j] = *(const bf16x8*)(pBh + off);
            bl4[j] = *(const bf16x8*)(pBl + off);
        }

        #pragma unroll
        for (int i = 0; i < 4; i++)
            #pragma unroll
            for (int j = 0; j < 4; j++) {
                acc[i][j] = __builtin_amdgcn_mfma_f32_16x16x32_bf16(ah[i], bh4[j], acc[i][j], 0, 0, 0);
                acc[i][j] = __builtin_amdgcn_mfma_f32_16x16x32_bf16(ah[i], bl4[j], acc[i][j], 0, 0, 0);
            }
    }
#undef LOAD_T

    // epilogue (C/D: col=lane&15, row=(lane>>4)*4+r)
    float bv[4];
    #pragma unroll
    for (int j = 0; j < 4; j++) bv[j] = bias[bn * 128 + wn + j * 16 + lr];
    #pragma unroll
    for (int i = 0; i < 4; i++) {
        const int rb = bm * 128 + wm + i * 16 + lg * 4;
        #pragma unroll
        for (int j = 0; j < 4; j++) {
            const int cg = bn * 128 + wn + j * 16 + lr;
            #pragma unroll
            for (int r = 0; r < 4; r++)
                out[OFF_TOKENS + (size_t)(rb + r) * 768 + cg] = acc[i][j][r] + bv[j];
        }
    }
}

// ---------------------------------------------------------------------------
// Side outputs: thread per (token, freq-pair); float2 stores for the repeat.
// ---------------------------------------------------------------------------
__global__ __launch_bounds__(256) void aux_kernel(float* __restrict__ out)
{
    const int idx = blockIdx.x * 256 + threadIdx.x;     // 0 .. 32768*32-1
    if (idx >= N_TOK * 32) return;
    const int n  = idx >> 5;
    const int jd = idx & 31;

    const int hp = (n & 1023) >> 5;
    const int wp = n & 31;

    const int coord = (jd < 16) ? hp : wp;
    const int j = jd & 15;
    const float freq = exp2f(-(float)j * 0.8304820237218406f);  // 10000^(-j/16)
    float s, c;
    sincosf((float)coord * freq, &s, &c);

    const long long off = (long long)n * 64 + jd * 2;
    *(float2*)(out + OFF_COS + off) = make_float2(c, c);
    *(float2*)(out + OFF_SIN + off) = make_float2(s, s);

    if (jd == 0) {
        out[OFF_COORDS + 2 * (long long)n]     = (float)hp;
        out[OFF_COORDS + 2 * (long long)n + 1] = (float)wp;
        out[OFF_ISP + n] = 1.0f;
    }
    if (jd == 1 && n < 33) {
        out[OFF_CU + n] = (float)(n * 1024);
    }
}

extern "C" void kernel_launch(void* const* d_in, const int* in_sizes, int n_in,
                              void* d_out, int out_size, void* d_ws, size_t ws_size,
                              hipStream_t stream) {
    const float* img  = (const float*)d_in[0];   // (32,3,512,512)
    const float* W    = (const float*)d_in[1];   // (768,768)
    const float* bias = (const float*)d_in[2];   // (768,)
    float* out = (float*)d_out;
    u16* wt = (u16*)d_ws;                        // 2*768*768*2 = 2.36 MB

    prep_w<<<768, 128, 0, stream>>>(W, wt);

    dim3 ggrid(6, 256);            // (N tiles, M tiles)
    patch_gemm_mfma<<<ggrid, 256, 0, stream>>>(img, wt, bias, out);

    const int aux_elems = N_TOK * 32;
    aux_kernel<<<(aux_elems + 255) / 256, 256, 0, stream>>>(out);
}

// Round 7
// 266.791 us; speedup vs baseline: 2.1788x; 1.0861x over previous
//
#include <hip/hip_runtime.h>
#include <hip/hip_bf16.h>

typedef unsigned short u16;
typedef unsigned int   u32;
typedef __bf16 bf16x8 __attribute__((ext_vector_type(8)));
typedef float  f32x4  __attribute__((ext_vector_type(4)));

#define N_TOK 32768
constexpr long long OFF_TOKENS = 0;                       // 32768*768
constexpr long long OFF_CU     = 25165824LL;              // 33
constexpr long long OFF_COORDS = 25165857LL;              // 32768*2
constexpr long long OFF_COS    = 25231393LL;              // 32768*64
constexpr long long OFF_SIN    = 27328545LL;              // 32768*64
constexpr long long OFF_ISP    = 29425697LL;              // 32768

__device__ __forceinline__ void split_bf16(float v, u16& h, u16& l) {
    __hip_bfloat16 bh = __float2bfloat16(v);
    float fh = __bfloat162float(bh);
    __hip_bfloat16 bl = __float2bfloat16(v - fh);
    h = __builtin_bit_cast(u16, bh);
    l = __builtin_bit_cast(u16, bl);
}

__device__ __forceinline__ u32 pk2(float lo, float hi) {
    u32 a = (u32)__builtin_bit_cast(u16, __float2bfloat16(lo));
    u32 b = (u32)__builtin_bit_cast(u16, __float2bfloat16(hi));
    return a | (b << 16);
}

// ---------------------------------------------------------------------------
// prep_w: build pre-swizzled per-(bn,kt) B-tile LDS images in workspace.
// Tile image (16KB): bytes [0,8K) = Bh, [8K,16K) = Bl; within each:
//   byte(n,k) = n*64 + (((k>>4) ^ ((n>>3)&1))<<5) + (k&15)*2
// This is EXACTLY the swizzled LDS layout the GEMM reads, so the GEMM can
// stage B with linear global_load_lds (wave-uniform dest + lane*16).
// Block = one (bn,kt) tile; coalesced W reads, LDS scatter, coalesced stores.
// ---------------------------------------------------------------------------
__global__ __launch_bounds__(256) void prep_w(const float* __restrict__ W,
                                              u16* __restrict__ wt2) {
    const int bid = blockIdx.x;           // 0..143 = bn*24 + kt
    const int bn  = bid / 24;
    const int kt  = bid - bn * 24;
    __shared__ u16 im[8192];              // [0,4096)=h image, [4096,8192)=l
    const int t  = threadIdx.x;
    const int k  = t >> 3;                // 0..31
    const int n0 = (t & 7) * 16;
    const float* src = W + (size_t)(kt * 32 + k) * 768 + bn * 128 + n0;
    #pragma unroll
    for (int e = 0; e < 16; e++) {
        const int n = n0 + e;
        u16 h, l;
        split_bf16(src[e], h, l);
        const int p = (n * 64 + (((k >> 4) ^ ((n >> 3) & 1)) << 5) + (k & 15) * 2) >> 1;
        im[p] = h;
        im[4096 + p] = l;
    }
    __syncthreads();
    uint4* g = (uint4*)(wt2 + (size_t)bid * 8192);
    const uint4* s = (const uint4*)im;
    #pragma unroll
    for (int i = 0; i < 4; i++) g[t + i * 256] = s[t + i * 256];
}

// ---------------------------------------------------------------------------
// Fused patchify + 2-pass split-bf16 MFMA GEMM (identical math to round 5:
// tokens = Ah·(Bh+Bl) + bias, bit-identical accumulation order).
// BM=128 BN=128 BK=32; 512 threads = 8 waves (2M x 4N), 64x32 per wave.
// Full A+B double-buffer -> ONE barrier per iter. B staged by
// global_load_lds from pre-swizzled tile images; A reg-pipelined depth-2.
// XCD-chunked block swizzle (grid 1536 = 8 XCD x 192).
// ---------------------------------------------------------------------------
__global__ __launch_bounds__(512, 4) void patch_gemm_mfma(
    const float* __restrict__ img, const u16* __restrict__ wt2,
    const float* __restrict__ bias, float* __restrict__ out)
{
    __shared__ __align__(16) char smem[49152];
    char* pA0 = smem;              // Ah[128][32] bf16, buf0
    char* pA1 = smem + 8192;
    char* pB0 = smem + 16384;      // Bh+Bl image, buf0 (16KB)
    char* pB1 = smem + 32768;

    // --- XCD-chunked swizzle: XCD x owns bm range [x*32, x*32+32) ---
    const int L   = blockIdx.x;           // 0..1535
    const int c   = (L & 7) * 192 + (L >> 3);
    const int bm  = c / 6;
    const int bn  = c - bm * 6;
    const int tb  = bn * 24;

    const int tid  = threadIdx.x;
    const int lane = tid & 63;
    const int wid  = tid >> 6;            // 0..7
    const int wm   = (wid >> 2) << 6;     // 0/64
    const int wn   = (wid & 3) << 5;      // 0/32/64/96
    const int lr   = lane & 15;
    const int lg   = lane >> 4;

    // A staging: thread = (row am, k-eighth aq); 8 contiguous fp32
    const int am = tid & 127;
    const int aq = tid >> 7;              // 0..3
    const int m  = bm * 128 + am;
    const int bb = m >> 10;
    const int hp = (m & 1023) >> 5;
    const int wq = m & 31;
    const float* abase = img + (size_t)bb * 786432 + (size_t)hp * 8192 + wq * 16;
    const int a_wb = am * 64 + (((aq >> 1) ^ ((am >> 3) & 1)) << 5) + ((aq & 1) << 4);

    // fragment-read byte offset (row base added per frag; row&8 == lr&8)
    const int a_rd = lr * 64 + (((lg >> 1) ^ ((lr >> 3) & 1)) << 5) + ((lg & 1) << 4);

    f32x4 acc[4][2];
    #pragma unroll
    for (int i = 0; i < 4; i++)
        #pragma unroll
        for (int j = 0; j < 2; j++) acc[i][j] = {0.f, 0.f, 0.f, 0.f};

    float4 A0a, A0b, A1a, A1b;

#define LOAD_A(ra, rb, T)                                                   \
    {   const float* ap = abase + ((T) >> 3) * 262144 +                     \
            (((T) & 7) * 2 + (aq >> 1)) * 512 + (aq & 1) * 8;               \
        ra = *(const float4*)ap;  rb = *(const float4*)(ap + 4); }

#define CVT_STORE(ra, rb, pdst)                                             \
    {   uint4 Hq;                                                           \
        Hq.x = pk2(ra.x, ra.y); Hq.y = pk2(ra.z, ra.w);                     \
        Hq.z = pk2(rb.x, rb.y); Hq.w = pk2(rb.z, rb.w);                     \
        *(uint4*)((pdst) + a_wb) = Hq; }

#define GLOADB(T, dst)                                                      \
    {   const char* s = (const char*)wt2 + (size_t)(tb + (T)) * 16384       \
                        + (wid << 11) + (lane << 4);                        \
        char* d = (dst) + (wid << 11);                                      \
        __builtin_amdgcn_global_load_lds(                                   \
            (const __attribute__((address_space(1))) u32*)s,                \
            (__attribute__((address_space(3))) u32*)d, 16, 0, 0);           \
        __builtin_amdgcn_global_load_lds(                                   \
            (const __attribute__((address_space(1))) u32*)(s + 1024),       \
            (__attribute__((address_space(3))) u32*)(d + 1024), 16, 0, 0); }

#define COMPUTE(pAc, pBc)                                                   \
    {   bf16x8 ahf[4], bhf[2], blf[2];                                      \
        _Pragma("unroll")                                                   \
        for (int i = 0; i < 4; i++)                                         \
            ahf[i] = *(const bf16x8*)((pAc) + ((wm + i * 16) << 6) + a_rd); \
        _Pragma("unroll")                                                   \
        for (int j = 0; j < 2; j++) {                                       \
            bhf[j] = *(const bf16x8*)((pBc) + ((wn + j * 16) << 6) + a_rd); \
            blf[j] = *(const bf16x8*)((pBc) + 8192 + ((wn + j * 16) << 6) + a_rd); \
        }                                                                   \
        _Pragma("unroll")                                                   \
        for (int i = 0; i < 4; i++)                                         \
            _Pragma("unroll")                                               \
            for (int j = 0; j < 2; j++) {                                   \
                acc[i][j] = __builtin_amdgcn_mfma_f32_16x16x32_bf16(ahf[i], bhf[j], acc[i][j], 0, 0, 0); \
                acc[i][j] = __builtin_amdgcn_mfma_f32_16x16x32_bf16(ahf[i], blf[j], acc[i][j], 0, 0, 0); \
            } }

    // ---- prologue: stage tile 0, preload tile 1 regs ----
    LOAD_A(A0a, A0b, 0);
    GLOADB(0, pB0);
    LOAD_A(A1a, A1b, 1);
    CVT_STORE(A0a, A0b, pA0);
    __syncthreads();

    // ---- main loop: 1 barrier/iter, unrolled x2 (static reg rotation) ----
    #pragma unroll 1
    for (int t = 0; t < 24; t += 2) {
        // even iter: compute buf0, stage t+1 -> buf1
        if (t < 23) { CVT_STORE(A1a, A1b, pA1); GLOADB(t + 1, pB1); }
        if (t < 22) LOAD_A(A0a, A0b, t + 2);
        COMPUTE(pA0, pB0);
        __syncthreads();
        // odd iter: compute buf1, stage t+2 -> buf0
        if (t + 1 < 23) { CVT_STORE(A0a, A0b, pA0); GLOADB(t + 2, pB0); }
        if (t + 1 < 22) LOAD_A(A1a, A1b, t + 3);
        COMPUTE(pA1, pB1);
        __syncthreads();
    }
#undef LOAD_A
#undef CVT_STORE
#undef GLOADB
#undef COMPUTE

    // ---- epilogue (C/D: col=lane&15, row=(lane>>4)*4+r) ----
    float bv[2];
    #pragma unroll
    for (int j = 0; j < 2; j++) bv[j] = bias[bn * 128 + wn + j * 16 + lr];
    #pragma unroll
    for (int i = 0; i < 4; i++) {
        const int rb = bm * 128 + wm + i * 16 + lg * 4;
        #pragma unroll
        for (int j = 0; j < 2; j++) {
            const int cg = bn * 128 + wn + j * 16 + lr;
            #pragma unroll
            for (int r = 0; r < 4; r++)
                out[OFF_TOKENS + (size_t)(rb + r) * 768 + cg] = acc[i][j][r] + bv[j];
        }
    }
}

// ---------------------------------------------------------------------------
// Side outputs: thread per (token, freq-pair); float2 stores for the repeat.
// ---------------------------------------------------------------------------
__global__ __launch_bounds__(256) void aux_kernel(float* __restrict__ out)
{
    const int idx = blockIdx.x * 256 + threadIdx.x;     // 0 .. 32768*32-1
    if (idx >= N_TOK * 32) return;
    const int n  = idx >> 5;
    const int jd = idx & 31;

    const int hp = (n & 1023) >> 5;
    const int wp = n & 31;

    const int coord = (jd < 16) ? hp : wp;
    const int j = jd & 15;
    const float freq = exp2f(-(float)j * 0.8304820237218406f);  // 10000^(-j/16)
    float s, c;
    sincosf((float)coord * freq, &s, &c);

    const long long off = (long long)n * 64 + jd * 2;
    *(float2*)(out + OFF_COS + off) = make_float2(c, c);
    *(float2*)(out + OFF_SIN + off) = make_float2(s, s);

    if (jd == 0) {
        out[OFF_COORDS + 2 * (long long)n]     = (float)hp;
        out[OFF_COORDS + 2 * (long long)n + 1] = (float)wp;
        out[OFF_ISP + n] = 1.0f;
    }
    if (jd == 1 && n < 33) {
        out[OFF_CU + n] = (float)(n * 1024);
    }
}

extern "C" void kernel_launch(void* const* d_in, const int* in_sizes, int n_in,
                              void* d_out, int out_size, void* d_ws, size_t ws_size,
                              hipStream_t stream) {
    const float* img  = (const float*)d_in[0];   // (32,3,512,512)
    const float* W    = (const float*)d_in[1];   // (768,768)
    const float* bias = (const float*)d_in[2];   // (768,)
    float* out = (float*)d_out;
    u16* wt2 = (u16*)d_ws;                       // 144 tiles * 16KB = 2.25 MB

    prep_w<<<144, 256, 0, stream>>>(W, wt2);

    patch_gemm_mfma<<<1536, 512, 0, stream>>>(img, wt2, bias, out);

    const int aux_elems = N_TOK * 32;
    aux_kernel<<<(aux_elems + 255) / 256, 256, 0, stream>>>(out);
}

// Round 8
// 263.112 us; speedup vs baseline: 2.2093x; 1.0140x over previous
//
#include <hip/hip_runtime.h>
#include <hip/hip_bf16.h>

typedef unsigned short u16;
typedef unsigned int   u32;
typedef __bf16 bf16x8 __attribute__((ext_vector_type(8)));
typedef float  f32x4  __attribute__((ext_vector_type(4)));

#define N_TOK 32768
constexpr long long OFF_TOKENS = 0;                       // 32768*768
constexpr long long OFF_CU     = 25165824LL;              // 33
constexpr long long OFF_COORDS = 25165857LL;              // 32768*2
constexpr long long OFF_COS    = 25231393LL;              // 32768*64
constexpr long long OFF_SIN    = 27328545LL;              // 32768*64
constexpr long long OFF_ISP    = 29425697LL;              // 32768

__device__ __forceinline__ void split_bf16(float v, u16& h, u16& l) {
    __hip_bfloat16 bh = __float2bfloat16(v);
    float fh = __bfloat162float(bh);
    __hip_bfloat16 bl = __float2bfloat16(v - fh);
    h = __builtin_bit_cast(u16, bh);
    l = __builtin_bit_cast(u16, bl);
}

__device__ __forceinline__ u32 pk2(float lo, float hi) {
    u32 a = (u32)__builtin_bit_cast(u16, __float2bfloat16(lo));
    u32 b = (u32)__builtin_bit_cast(u16, __float2bfloat16(hi));
    return a | (b << 16);
}

// ---------------------------------------------------------------------------
// prep_w: build pre-swizzled per-(bn,kt) B-tile LDS images in workspace.
// Tile image (16KB): bytes [0,8K) = Bh, [8K,16K) = Bl; within each:
//   byte(n,k) = n*64 + (((k>>4) ^ ((n>>3)&1))<<5) + (k&15)*2
// Exactly the swizzled LDS layout the GEMM reads -> GEMM stages B with
// linear global_load_lds (wave-uniform dest + lane*16).
// ---------------------------------------------------------------------------
__global__ __launch_bounds__(256) void prep_w(const float* __restrict__ W,
                                              u16* __restrict__ wt2) {
    const int bid = blockIdx.x;           // 0..143 = bn*24 + kt
    const int bn  = bid / 24;
    const int kt  = bid - bn * 24;
    __shared__ u16 im[8192];              // [0,4096)=h image, [4096,8192)=l
    const int t  = threadIdx.x;
    const int k  = t >> 3;                // 0..31
    const int n0 = (t & 7) * 16;
    const float* src = W + (size_t)(kt * 32 + k) * 768 + bn * 128 + n0;
    #pragma unroll
    for (int e = 0; e < 16; e++) {
        const int n = n0 + e;
        u16 h, l;
        split_bf16(src[e], h, l);
        const int p = (n * 64 + (((k >> 4) ^ ((n >> 3) & 1)) << 5) + (k & 15) * 2) >> 1;
        im[p] = h;
        im[4096 + p] = l;
    }
    __syncthreads();
    uint4* g = (uint4*)(wt2 + (size_t)bid * 8192);
    const uint4* s = (const uint4*)im;
    #pragma unroll
    for (int i = 0; i < 4; i++) g[t + i * 256] = s[t + i * 256];
}

// ---------------------------------------------------------------------------
// Fused patchify + 2-pass split-bf16 MFMA GEMM (math identical to round 5/7).
// BM=128 BN=128 BK=32; 512 threads = 8 waves (2M x 4N), 64x32 per wave.
// 3-deep LDS pipeline (A and B) + counted vmcnt(6) + raw s_barrier (T4):
// barrier never drains the newest 6 VMEM ops = {LOAD_A(t+3), GLOADB(t+2),
// LOAD_A(t+2)}; GLOADB(t+1) (needed next iter) is 7th-newest -> drained.
// sched_barrier(0) pins the GLOADB-before-LOAD_A issue order the count
// relies on. XCD-chunked block swizzle (grid 1536 = 8 XCD x 192).
// ---------------------------------------------------------------------------
__global__ __launch_bounds__(512, 4) void patch_gemm_mfma(
    const float* __restrict__ img, const u16* __restrict__ wt2,
    const float* __restrict__ bias, float* __restrict__ out)
{
    __shared__ __align__(16) char smem[73728];
    char* pA0 = smem;               // Ah[128][32] bf16 (8KB each)
    char* pA1 = smem + 8192;
    char* pA2 = smem + 16384;
    char* pB0 = smem + 24576;       // Bh+Bl image (16KB each)
    char* pB1 = smem + 40960;
    char* pB2 = smem + 57344;

    // --- XCD-chunked swizzle: XCD x owns bm range [x*32, x*32+32) ---
    const int L   = blockIdx.x;           // 0..1535
    const int c   = (L & 7) * 192 + (L >> 3);
    const int bm  = c / 6;
    const int bn  = c - bm * 6;
    const int tb  = bn * 24;

    const int tid  = threadIdx.x;
    const int lane = tid & 63;
    const int wid  = tid >> 6;            // 0..7
    const int wm   = (wid >> 2) << 6;     // 0/64
    const int wn   = (wid & 3) << 5;      // 0/32/64/96
    const int lr   = lane & 15;
    const int lg   = lane >> 4;

    // A staging: thread = (row am, k-eighth aq); 8 contiguous fp32
    const int am = tid & 127;
    const int aq = tid >> 7;              // 0..3
    const int m  = bm * 128 + am;
    const int bb = m >> 10;
    const int hp = (m & 1023) >> 5;
    const int wq = m & 31;
    const float* abase = img + (size_t)bb * 786432 + (size_t)hp * 8192 + wq * 16;
    const int a_wb = am * 64 + (((aq >> 1) ^ ((am >> 3) & 1)) << 5) + ((aq & 1) << 4);

    // fragment-read byte offset (row base added per frag; row&8 == lr&8)
    const int a_rd = lr * 64 + (((lg >> 1) ^ ((lr >> 3) & 1)) << 5) + ((lg & 1) << 4);

    f32x4 acc[4][2];
    #pragma unroll
    for (int i = 0; i < 4; i++)
        #pragma unroll
        for (int j = 0; j < 2; j++) acc[i][j] = {0.f, 0.f, 0.f, 0.f};

    float4 A0a, A0b, A1a, A1b, A2a, A2b;    // 3-slot A register rotation

#define LOAD_A(ra, rb, T)                                                   \
    {   const float* ap = abase + ((T) >> 3) * 262144 +                     \
            (((T) & 7) * 2 + (aq >> 1)) * 512 + (aq & 1) * 8;               \
        ra = *(const float4*)ap;  rb = *(const float4*)(ap + 4); }

#define CVT_STORE(ra, rb, pdst)                                             \
    {   uint4 Hq;                                                           \
        Hq.x = pk2(ra.x, ra.y); Hq.y = pk2(ra.z, ra.w);                     \
        Hq.z = pk2(rb.x, rb.y); Hq.w = pk2(rb.z, rb.w);                     \
        *(uint4*)((pdst) + a_wb) = Hq; }

#define GLOADB(T, dst)                                                      \
    {   const char* s = (const char*)wt2 + (size_t)(tb + (T)) * 16384       \
                        + (wid << 11) + (lane << 4);                        \
        char* d = (dst) + (wid << 11);                                      \
        __builtin_amdgcn_global_load_lds(                                   \
            (const __attribute__((address_space(1))) u32*)s,                \
            (__attribute__((address_space(3))) u32*)d, 16, 0, 0);           \
        __builtin_amdgcn_global_load_lds(                                   \
            (const __attribute__((address_space(1))) u32*)(s + 1024),       \
            (__attribute__((address_space(3))) u32*)(d + 1024), 16, 0, 0); }

#define COMPUTE(pAc, pBc)                                                   \
    {   bf16x8 ahf[4], bhf[2], blf[2];                                      \
        _Pragma("unroll")                                                   \
        for (int i = 0; i < 4; i++)                                         \
            ahf[i] = *(const bf16x8*)((pAc) + ((wm + i * 16) << 6) + a_rd); \
        _Pragma("unroll")                                                   \
        for (int j = 0; j < 2; j++) {                                       \
            bhf[j] = *(const bf16x8*)((pBc) + ((wn + j * 16) << 6) + a_rd); \
            blf[j] = *(const bf16x8*)((pBc) + 8192 + ((wn + j * 16) << 6) + a_rd); \
        }                                                                   \
        _Pragma("unroll")                                                   \
        for (int i = 0; i < 4; i++)                                         \
            _Pragma("unroll")                                               \
            for (int j = 0; j < 2; j++) {                                   \
                acc[i][j] = __builtin_amdgcn_mfma_f32_16x16x32_bf16(ahf[i], bhf[j], acc[i][j], 0, 0, 0); \
                acc[i][j] = __builtin_amdgcn_mfma_f32_16x16x32_bf16(ahf[i], blf[j], acc[i][j], 0, 0, 0); \
            } }

// iter T: CVT(tile T+1 -> pA[(T+1)%3]); GLOADB(T+2 -> pB[(T+2)%3]);
//         LOAD_A(tile T+3 -> slot[T%3]); COMPUTE(pA[T%3], pB[T%3]);
//         counted-vmcnt barrier.
#define ITER(T, Ca, Cb, La, Lb, PACV, PBGL, PAC, PBC)                       \
    {   if ((T) + 1 < 24) CVT_STORE(Ca, Cb, PACV);                          \
        if ((T) + 2 < 24) GLOADB((T) + 2, PBGL);                            \
        __builtin_amdgcn_sched_barrier(0);                                  \
        if ((T) + 3 < 24) LOAD_A(La, Lb, (T) + 3);                          \
        COMPUTE(PAC, PBC);                                                  \
        asm volatile("s_waitcnt vmcnt(6) lgkmcnt(0)" ::: "memory");         \
        __builtin_amdgcn_s_barrier();                                       \
    }

    // ---- prologue: tiles 0,1 -> LDS-B in flight; A slots 0,1,2 loaded ----
    GLOADB(0, pB0);
    LOAD_A(A0a, A0b, 0);
    GLOADB(1, pB1);
    LOAD_A(A1a, A1b, 1);
    LOAD_A(A2a, A2b, 2);
    CVT_STORE(A0a, A0b, pA0);   // implicit wait on A0 drains GLOADB(0) too
    asm volatile("s_waitcnt vmcnt(6) lgkmcnt(0)" ::: "memory");
    __builtin_amdgcn_s_barrier();

    // ---- main loop: period-3 rotation, 24 iters = 8 x 3 ----
    #pragma unroll 1
    for (int t = 0; t < 24; t += 3) {
        ITER(t,     A1a, A1b, A0a, A0b, pA1, pB2, pA0, pB0);
        ITER(t + 1, A2a, A2b, A1a, A1b, pA2, pB0, pA1, pB1);
        ITER(t + 2, A0a, A0b, A2a, A2b, pA0, pB1, pA2, pB2);
    }
#undef ITER
#undef LOAD_A
#undef CVT_STORE
#undef GLOADB
#undef COMPUTE

    // ---- epilogue (C/D: col=lane&15, row=(lane>>4)*4+r) ----
    float bv[2];
    #pragma unroll
    for (int j = 0; j < 2; j++) bv[j] = bias[bn * 128 + wn + j * 16 + lr];
    #pragma unroll
    for (int i = 0; i < 4; i++) {
        const int rb = bm * 128 + wm + i * 16 + lg * 4;
        #pragma unroll
        for (int j = 0; j < 2; j++) {
            const int cg = bn * 128 + wn + j * 16 + lr;
            #pragma unroll
            for (int r = 0; r < 4; r++)
                out[OFF_TOKENS + (size_t)(rb + r) * 768 + cg] = acc[i][j][r] + bv[j];
        }
    }
}

// ---------------------------------------------------------------------------
// Side outputs: thread per (token, freq-pair); float2 stores for the repeat.
// ---------------------------------------------------------------------------
__global__ __launch_bounds__(256) void aux_kernel(float* __restrict__ out)
{
    const int idx = blockIdx.x * 256 + threadIdx.x;     // 0 .. 32768*32-1
    if (idx >= N_TOK * 32) return;
    const int n  = idx >> 5;
    const int jd = idx & 31;

    const int hp = (n & 1023) >> 5;
    const int wp = n & 31;

    const int coord = (jd < 16) ? hp : wp;
    const int j = jd & 15;
    const float freq = exp2f(-(float)j * 0.8304820237218406f);  // 10000^(-j/16)
    float s, c;
    sincosf((float)coord * freq, &s, &c);

    const long long off = (long long)n * 64 + jd * 2;
    *(float2*)(out + OFF_COS + off) = make_float2(c, c);
    *(float2*)(out + OFF_SIN + off) = make_float2(s, s);

    if (jd == 0) {
        out[OFF_COORDS + 2 * (long long)n]     = (float)hp;
        out[OFF_COORDS + 2 * (long long)n + 1] = (float)wp;
        out[OFF_ISP + n] = 1.0f;
    }
    if (jd == 1 && n < 33) {
        out[OFF_CU + n] = (float)(n * 1024);
    }
}

extern "C" void kernel_launch(void* const* d_in, const int* in_sizes, int n_in,
                              void* d_out, int out_size, void* d_ws, size_t ws_size,
                              hipStream_t stream) {
    const float* img  = (const float*)d_in[0];   // (32,3,512,512)
    const float* W    = (const float*)d_in[1];   // (768,768)
    const float* bias = (const float*)d_in[2];   // (768,)
    float* out = (float*)d_out;
    u16* wt2 = (u16*)d_ws;                       // 144 tiles * 16KB = 2.25 MB

    prep_w<<<144, 256, 0, stream>>>(W, wt2);

    patch_gemm_mfma<<<1536, 512, 0, stream>>>(img, wt2, bias, out);

    const int aux_elems = N_TOK * 32;
    aux_kernel<<<(aux_elems + 255) / 256, 256, 0, stream>>>(out);
}